// Round 18
// baseline (805.401 us; speedup 1.0000x reference)
//
#include <hip/hip_runtime.h>
#include <stdint.h>

#define THREADS 256
#define BR      64

// d_ws layout: bf16 weights as MFMA A-fragments, CONTIGUOUS per wave (ng).
// Per-ng stream (200KB): [layer0: 8KB][layer1..6: 32KB each].
// Fragment = 1KB: lane (hi*32+l31) holds n = base_n + l31, k = kk*16 + hi*8 + e.
// Within a layer, frag index = (c*4+kk)*2 + ft  (ft = which 32-neuron half).
#define NG_STRIDE 204800
#define WS_WOUT   819200                 // layer7: 16 kk x 1 frag = 16KB
#define WS_TOTAL  (WS_WOUT + 16384)

// act LDS (one 32KB buffer):
//   phase 0 (enc -> layer0): row-major [64][512B], 8B XOR swizzle
//     byte^=((row&15)<<3)  (R7/R12-proven pair).
//   phase 1+ : B-FRAGMENT layout, frag(ks, rb) at (ks*2+rb)*1024 (rb=0..1);
//     lane L holds act[rb*32+(L&31)][ks*16+(L>>5)*8+e] at byte L*16+e*2.
//     Reads = single ds_read_b128 at lane*16 + imm.

typedef short bf16x8 __attribute__((ext_vector_type(8)));
typedef short bf16x4 __attribute__((ext_vector_type(4)));
typedef float f32x16 __attribute__((ext_vector_type(16)));
typedef float f32x4v __attribute__((ext_vector_type(4)));

__device__ __forceinline__ unsigned short f2bf(float f) {
    union { float f; unsigned int u; } v; v.f = f;
    unsigned int u = v.u;
    u += 0x7fffu + ((u >> 16) & 1u);   // round-to-nearest-even
    return (unsigned short)(u >> 16);
}
__device__ __forceinline__ unsigned int cvt_pk_bf16(float lo, float hi) {
    unsigned int d;
    asm("v_cvt_pk_bf16_f32 %0, %1, %2" : "=v"(d) : "v"(lo), "v"(hi));
    return d;
}
__device__ __forceinline__ bf16x8 ld_act2(const unsigned char* lo,
                                          const unsigned char* hi) {
    bf16x4 a = *(const bf16x4*)lo;
    bf16x4 b = *(const bf16x4*)hi;
    return __builtin_shufflevector(a, b, 0, 1, 2, 3, 4, 5, 6, 7);
}
// layer barrier: LDS-only fence (R14/R15-proven). No vmcnt drain.
__device__ __forceinline__ void lds_barrier() {
    asm volatile("s_waitcnt lgkmcnt(0)" ::: "memory");
    __builtin_amdgcn_s_barrier();
}

// ---------------------------------------------------------------------------
// prep: fp32 weights -> bf16 MFMA A-fragment streams in ws (R12-identical)
// ---------------------------------------------------------------------------
__global__ void prep_kernel(const float* __restrict__ W_in,
                            const float* __restrict__ W_hid,
                            const float* __restrict__ W_out,
                            unsigned char* __restrict__ ws) {
    int id = blockIdx.x * 256 + threadIdx.x;
    if (id < 16384) {                        // W_in: k(64 pad) x n(256)
        int n = id & 255, k = id >> 8;
        int ng = n >> 6, ft = (n >> 5) & 1, ln = n & 31;
        int kk = k >> 4, hi = (k >> 3) & 1, e = k & 7;
        float v = (k < 40) ? W_in[k * 256 + n] : 0.f;
        *(unsigned short*)(ws + ng * NG_STRIDE + (kk * 2 + ft) * 1024
                           + (hi * 32 + ln) * 16 + e * 2) = f2bf(v);
    } else if (id < 16384 + 393216) {        // W_hid: 6 x k(256) x n(256)
        int e2 = id - 16384;
        int l = e2 >> 16, r = e2 & 65535;
        int k = r >> 8, n = r & 255;
        int c = k >> 6, kk = (k >> 4) & 3, hi = (k >> 3) & 1, e = k & 7;
        int ng = n >> 6, ft = (n >> 5) & 1, ln = n & 31;
        float v = W_hid[l * 65536 + k * 256 + n];
        *(unsigned short*)(ws + ng * NG_STRIDE + 8192 + l * 32768
                           + ((c * 4 + kk) * 2 + ft) * 1024
                           + (hi * 32 + ln) * 16 + e * 2) = f2bf(v);
    } else if (id < 16384 + 393216 + 8192) { // W_out: k(256) x n(3 -> 32 pad)
        int e3 = id - 16384 - 393216;
        int n = e3 >> 8, k = e3 & 255;
        int kk = k >> 4, hi = (k >> 3) & 1, e = k & 7;
        float v = (n < 3) ? W_out[k * 3 + n] : 0.f;
        *(unsigned short*)(ws + WS_WOUT + kk * 1024
                           + (hi * 32 + n) * 16 + e * 2) = f2bf(v);
    }
}

// ---------------------------------------------------------------------------
// shared pieces (R12 mappings, rb = 2)
// ---------------------------------------------------------------------------
__device__ __forceinline__ void bias_init(const float* __restrict__ bp,
                                          f32x16 (&acc)[2][2], int nblk, int hi) {
    #pragma unroll
    for (int tn = 0; tn < 2; ++tn) {
        #pragma unroll
        for (int g4 = 0; g4 < 4; ++g4) {
            f32x4v bv = *(const f32x4v*)(bp + nblk + tn * 32 + g4 * 8 + hi * 4);
            #pragma unroll
            for (int tr = 0; tr < 2; ++tr) {
                #pragma unroll
                for (int j = 0; j < 4; ++j)
                    acc[tn][tr][g4 * 4 + j] = bv[j];
            }
        }
    }
}

__device__ __forceinline__ void epilogue_frag(f32x16 (&acc)[2][2],
                                              unsigned char* actL,
                                              int vW, int wv) {
    #pragma unroll
    for (int tr = 0; tr < 2; ++tr) {
        #pragma unroll
        for (int tn = 0; tn < 2; ++tn) {
            #pragma unroll
            for (int g4 = 0; g4 < 4; ++g4) {
                float v0 = fmaxf(acc[tn][tr][g4 * 4 + 0], 0.f);
                float v1 = fmaxf(acc[tn][tr][g4 * 4 + 1], 0.f);
                float v2 = fmaxf(acc[tn][tr][g4 * 4 + 2], 0.f);
                float v3 = fmaxf(acc[tn][tr][g4 * 4 + 3], 0.f);
                const int ks  = wv * 4 + tn * 2 + (g4 >> 1);
                const int off = (ks * 2 + tr) * 1024 + ((g4 & 1) << 9);
                uint2 u; u.x = cvt_pk_bf16(v0, v1); u.y = cvt_pk_bf16(v2, v3);
                *(uint2*)&actL[vW + off] = u;
            }
        }
    }
}

// one hidden layer: frag B-reads (single ds_read_b128), R12-proven body
__device__ __forceinline__ void hidden_layer(const unsigned char* __restrict__ wl,
                                             const float* __restrict__ bp,
                                             unsigned char* actL, f32x16 (&acc)[2][2],
                                             int vB, int vW, int wv,
                                             int nblk, int hi) {
    bias_init(bp, acc, nblk, hi);
    __builtin_amdgcn_s_setprio(1);
    #pragma unroll
    for (int s = 0; s < 16; ++s) {
        const unsigned char* fp = wl + s * 2048;
        bf16x8 a0 = *(const bf16x8*)(fp);
        bf16x8 a1 = *(const bf16x8*)(fp + 1024);
        const int fo = s * 2048;
        #pragma unroll
        for (int tr = 0; tr < 2; ++tr) {
            bf16x8 b = *(const bf16x8*)&actL[vB + fo + tr * 1024];
            acc[0][tr] = __builtin_amdgcn_mfma_f32_32x32x16_bf16(a0, b, acc[0][tr], 0, 0, 0);
            acc[1][tr] = __builtin_amdgcn_mfma_f32_32x32x16_bf16(a1, b, acc[1][tr], 0, 0, 0);
        }
    }
    __builtin_amdgcn_s_setprio(0);
    lds_barrier();                        // reads done; safe to overwrite
    epilogue_frag(acc, actL, vW, wv);
    lds_barrier();                        // frags visible to all waves
}

// ---------------------------------------------------------------------------
// fused MLP: enc -> 7x(GEMM+bias+relu) -> tanh/100. 64 rows/block,
// 4 waves x (64n x 64r), 3 blocks/CU = 3 waves/SIMD (lean reg set).
// ---------------------------------------------------------------------------
__global__ __launch_bounds__(THREADS, 3)
void nerf_main(const float* __restrict__ x,
               const float* __restrict__ b_in,
               const float* __restrict__ b_hid,
               const float* __restrict__ b_out,
               const unsigned char* __restrict__ ws,
               float* __restrict__ out, int nrows) {
    __shared__ __align__(16) unsigned char actL[32768];

    const int tid  = threadIdx.x;
    const int lane = tid & 63;
    const int wv   = tid >> 6;            // 0..3 (= ng)
    const int l31  = lane & 31;
    const int hi   = lane >> 5;
    const int hi16 = hi << 4;
    const int rswz  = (l31 & 15) << 3;    // 8B-granular act swizzle (phase 0)
    const int rswz2 = rswz ^ 8;
    const int nblk = wv * 64;
    const int gr0  = blockIdx.x * BR;

    const int vB = lane * 16;             // frag B-read base
    const int vW = l31 * 16 + hi * 8;     // frag epilogue write base

    // ---- positional encoding: row-major body, one pass (rows 0..63) ----
    {
        const int rr = tid >> 2;          // 0..63
        const int part = tid & 3;
        const int co = part >> 1, hf = part & 1;
        const int grow = gr0 + rr;
        float xv = (grow < nrows) ? x[(size_t)grow * 2 + co] : 0.f;
        const int rowo = rr * 512;
        const int rsw = (rr & 15) << 3;
        const int kb = co * 20 + hf * 10;
        float vv[10];
        #pragma unroll
        for (int f = 0; f < 10; ++f) {
            float ang = xv * (float)(1 << f);
            vv[f] = hf ? __cosf(ang) : __sinf(ang);
        }
        #pragma unroll
        for (int p = 0; p < 5; ++p) {
            unsigned int u = cvt_pk_bf16(vv[2 * p], vv[2 * p + 1]);
            int byte = (kb + 2 * p) * 2;
            *(unsigned int*)&actL[rowo + (byte ^ rsw)] = u;
        }
        int z = 80 + part * 12;           // zero-pad bytes [80,128)
        *(unsigned int*)&actL[rowo + ((z    ) ^ rsw)] = 0u;
        *(unsigned int*)&actL[rowo + ((z + 4) ^ rsw)] = 0u;
        *(unsigned int*)&actL[rowo + ((z + 8) ^ rsw)] = 0u;
    }
    __syncthreads();

    f32x16 acc[2][2];
    const unsigned char* wstream = ws + wv * NG_STRIDE + lane * 16;

    // ---- layer 0: R7-proven row-major B-reads; frag epilogue ----
    {
        bias_init(b_in, acc, nblk, hi);
        int olo[4], ohi[4];
        #pragma unroll
        for (int kk = 0; kk < 4; ++kk) {
            const int bo = kk * 32 + hi16;
            olo[kk] = l31 * 512 + (bo ^ rswz);
            ohi[kk] = l31 * 512 + (bo ^ rswz2);
        }
        __builtin_amdgcn_s_setprio(1);
        #pragma unroll
        for (int kk = 0; kk < 4; ++kk) {
            const unsigned char* fp = wstream + kk * 2048;
            bf16x8 a0 = *(const bf16x8*)(fp);
            bf16x8 a1 = *(const bf16x8*)(fp + 1024);
            #pragma unroll
            for (int tr = 0; tr < 2; ++tr) {
                bf16x8 b = ld_act2(&actL[olo[kk] + tr * 16384],
                                   &actL[ohi[kk] + tr * 16384]);
                acc[0][tr] = __builtin_amdgcn_mfma_f32_32x32x16_bf16(a0, b, acc[0][tr], 0, 0, 0);
                acc[1][tr] = __builtin_amdgcn_mfma_f32_32x32x16_bf16(a1, b, acc[1][tr], 0, 0, 0);
            }
        }
        __builtin_amdgcn_s_setprio(0);
        lds_barrier();
        epilogue_frag(acc, actL, vW, wv);
        lds_barrier();
        wstream += 8192;
    }

    // ---- layers 1..6 ----
    #pragma unroll 1
    for (int l = 0; l < 6; ++l) {
        hidden_layer(wstream, b_hid + l * 256,
                     actL, acc, vB, vW, wv, nblk, hi);
        wstream += 32768;
    }

    // ---- layer 7: frag B-reads -> tanh/100 -> out ----
    if (wv < 2) {
        f32x16 c0, c1;
        #pragma unroll
        for (int j = 0; j < 16; ++j) { c0[j] = 0.f; c1[j] = 0.f; }
        const unsigned char* wo = ws + WS_WOUT + lane * 16;
        #pragma unroll
        for (int kk = 0; kk < 16; ++kk) {
            bf16x8 a = *(const bf16x8*)(wo + kk * 1024);
            bf16x8 b = *(const bf16x8*)&actL[vB + (kk * 2 + wv) * 1024];
            if (kk & 1) c1 = __builtin_amdgcn_mfma_f32_32x32x16_bf16(a, b, c1, 0, 0, 0);
            else        c0 = __builtin_amdgcn_mfma_f32_32x32x16_bf16(a, b, c0, 0, 0, 0);
        }
        if (hi == 0) {
            const int row = gr0 + wv * 32 + l31;
            if (row < nrows) {
                float* op = out + (size_t)row * 3;
                #pragma unroll
                for (int j = 0; j < 3; ++j)
                    op[j] = tanhf(c0[j] + c1[j] + b_out[j]) * 0.01f;
            }
        }
    }
}

extern "C" void kernel_launch(void* const* d_in, const int* in_sizes, int n_in,
                              void* d_out, int out_size, void* d_ws, size_t ws_size,
                              hipStream_t stream) {
    (void)n_in; (void)out_size;
    const float* x     = (const float*)d_in[0];
    const float* W_in  = (const float*)d_in[1];
    const float* b_in  = (const float*)d_in[2];
    const float* W_hid = (const float*)d_in[3];
    const float* b_hid = (const float*)d_in[4];
    const float* W_out = (const float*)d_in[5];
    const float* b_out = (const float*)d_in[6];
    unsigned char* ws  = (unsigned char*)d_ws;
    float* out = (float*)d_out;

    if (ws_size < (size_t)WS_TOTAL) return;

    const int nrows = in_sizes[0] / 2;                // total points
    const int grid  = (nrows + BR - 1) / BR;

    prep_kernel<<<1632, 256, 0, stream>>>(W_in, W_hid, W_out, ws);
    nerf_main<<<grid, THREADS, 0, stream>>>(x, b_in, b_hid, b_out, ws, out, nrows);
}

// Round 19
// 702.923 us; speedup vs baseline: 1.1458x; 1.1458x over previous
//
#include <hip/hip_runtime.h>
#include <stdint.h>

#define THREADS 256
#define BR      160

// d_ws layout: bf16 weights as MFMA A-fragments, CONTIGUOUS per wave (ng).
// Per-ng stream (200KB): [layer0: 8KB][layer1..6: 32KB each].
// Fragment = 1KB: lane (hi*32+l31) holds n = base_n + l31, k = kk*16 + hi*8 + e.
// Within a layer, frag index = (c*4+kk)*2 + ft  (ft = which 32-neuron half).
#define NG_STRIDE 204800
#define WS_WOUT   819200                 // layer7: 16 kk x 1 frag = 16KB
#define WS_TOTAL  (WS_WOUT + 16384)

// act LDS (one 80KB buffer, R12 layout with 5 row-blocks):
//   phase 0 (enc -> layer0): row-major [160][512B], 8B XOR swizzle
//     byte^=((row&15)<<3).
//   phase 1+ : B-FRAGMENT layout, frag(ks, rb) at (ks*5+rb)*1024 (rb=0..4);
//     lane L holds act[rb*32+(L&31)][ks*16+(L>>5)*8+e] at byte L*16+e*2.
//     Reads = single ds_read_b128 at lane*16 + offset.

typedef short bf16x8 __attribute__((ext_vector_type(8)));
typedef short bf16x4 __attribute__((ext_vector_type(4)));
typedef float f32x16 __attribute__((ext_vector_type(16)));
typedef float f32x4v __attribute__((ext_vector_type(4)));

__device__ __forceinline__ unsigned short f2bf(float f) {
    union { float f; unsigned int u; } v; v.f = f;
    unsigned int u = v.u;
    u += 0x7fffu + ((u >> 16) & 1u);   // round-to-nearest-even
    return (unsigned short)(u >> 16);
}
__device__ __forceinline__ unsigned int cvt_pk_bf16(float lo, float hi) {
    unsigned int d;
    asm("v_cvt_pk_bf16_f32 %0, %1, %2" : "=v"(d) : "v"(lo), "v"(hi));
    return d;
}
__device__ __forceinline__ bf16x8 ld_act2(const unsigned char* lo,
                                          const unsigned char* hi) {
    bf16x4 a = *(const bf16x4*)lo;
    bf16x4 b = *(const bf16x4*)hi;
    return __builtin_shufflevector(a, b, 0, 1, 2, 3, 4, 5, 6, 7);
}

// ---------------------------------------------------------------------------
// prep: fp32 weights -> bf16 MFMA A-fragment streams in ws (R12-identical)
// ---------------------------------------------------------------------------
__global__ void prep_kernel(const float* __restrict__ W_in,
                            const float* __restrict__ W_hid,
                            const float* __restrict__ W_out,
                            unsigned char* __restrict__ ws) {
    int id = blockIdx.x * 256 + threadIdx.x;
    if (id < 16384) {                        // W_in: k(64 pad) x n(256)
        int n = id & 255, k = id >> 8;
        int ng = n >> 6, ft = (n >> 5) & 1, ln = n & 31;
        int kk = k >> 4, hi = (k >> 3) & 1, e = k & 7;
        float v = (k < 40) ? W_in[k * 256 + n] : 0.f;
        *(unsigned short*)(ws + ng * NG_STRIDE + (kk * 2 + ft) * 1024
                           + (hi * 32 + ln) * 16 + e * 2) = f2bf(v);
    } else if (id < 16384 + 393216) {        // W_hid: 6 x k(256) x n(256)
        int e2 = id - 16384;
        int l = e2 >> 16, r = e2 & 65535;
        int k = r >> 8, n = r & 255;
        int c = k >> 6, kk = (k >> 4) & 3, hi = (k >> 3) & 1, e = k & 7;
        int ng = n >> 6, ft = (n >> 5) & 1, ln = n & 31;
        float v = W_hid[l * 65536 + k * 256 + n];
        *(unsigned short*)(ws + ng * NG_STRIDE + 8192 + l * 32768
                           + ((c * 4 + kk) * 2 + ft) * 1024
                           + (hi * 32 + ln) * 16 + e * 2) = f2bf(v);
    } else if (id < 16384 + 393216 + 8192) { // W_out: k(256) x n(3 -> 32 pad)
        int e3 = id - 16384 - 393216;
        int n = e3 >> 8, k = e3 & 255;
        int kk = k >> 4, hi = (k >> 3) & 1, e = k & 7;
        float v = (n < 3) ? W_out[k * 3 + n] : 0.f;
        *(unsigned short*)(ws + WS_WOUT + kk * 1024
                           + (hi * 32 + n) * 16 + e * 2) = f2bf(v);
    }
}

// ---------------------------------------------------------------------------
// shared pieces (R12 mappings, tr extent 5)
// ---------------------------------------------------------------------------
__device__ __forceinline__ void bias_init(const float* __restrict__ bp,
                                          f32x16 (&acc)[2][5], int nblk, int hi) {
    #pragma unroll
    for (int tn = 0; tn < 2; ++tn) {
        #pragma unroll
        for (int g4 = 0; g4 < 4; ++g4) {
            f32x4v bv = *(const f32x4v*)(bp + nblk + tn * 32 + g4 * 8 + hi * 4);
            #pragma unroll
            for (int tr = 0; tr < 5; ++tr) {
                #pragma unroll
                for (int j = 0; j < 4; ++j)
                    acc[tn][tr][g4 * 4 + j] = bv[j];
            }
        }
    }
}

__device__ __forceinline__ void epilogue_frag(f32x16 (&acc)[2][5],
                                              unsigned char* actL,
                                              int vW, int wv) {
    #pragma unroll
    for (int tr = 0; tr < 5; ++tr) {
        #pragma unroll
        for (int tn = 0; tn < 2; ++tn) {
            #pragma unroll
            for (int g4 = 0; g4 < 4; ++g4) {
                float v0 = fmaxf(acc[tn][tr][g4 * 4 + 0], 0.f);
                float v1 = fmaxf(acc[tn][tr][g4 * 4 + 1], 0.f);
                float v2 = fmaxf(acc[tn][tr][g4 * 4 + 2], 0.f);
                float v3 = fmaxf(acc[tn][tr][g4 * 4 + 3], 0.f);
                const int ks  = wv * 4 + tn * 2 + (g4 >> 1);
                const int off = (ks * 5 + tr) * 1024 + ((g4 & 1) << 9);
                uint2 u; u.x = cvt_pk_bf16(v0, v1); u.y = cvt_pk_bf16(v2, v3);
                *(uint2*)&actL[vW + off] = u;
            }
        }
    }
}

// one hidden layer: frag B-reads (single ds_read_b128), R12-proven body
__device__ __forceinline__ void hidden_layer(const unsigned char* __restrict__ wl,
                                             const float* __restrict__ bp,
                                             unsigned char* actL, f32x16 (&acc)[2][5],
                                             int vB, int vW, int wv,
                                             int nblk, int hi) {
    bias_init(bp, acc, nblk, hi);
    __builtin_amdgcn_s_setprio(1);
    #pragma unroll
    for (int s = 0; s < 16; ++s) {
        const unsigned char* fp = wl + s * 2048;
        bf16x8 a0 = *(const bf16x8*)(fp);
        bf16x8 a1 = *(const bf16x8*)(fp + 1024);
        const int fo = s * 5120;
        #pragma unroll
        for (int tr = 0; tr < 5; ++tr) {
            bf16x8 b = *(const bf16x8*)&actL[vB + fo + tr * 1024];
            acc[0][tr] = __builtin_amdgcn_mfma_f32_32x32x16_bf16(a0, b, acc[0][tr], 0, 0, 0);
            acc[1][tr] = __builtin_amdgcn_mfma_f32_32x32x16_bf16(a1, b, acc[1][tr], 0, 0, 0);
        }
    }
    __builtin_amdgcn_s_setprio(0);
    __syncthreads();   // all waves done READING act
    epilogue_frag(acc, actL, vW, wv);
    __syncthreads();   // frags visible to all waves
}

// ---------------------------------------------------------------------------
// fused MLP: enc -> 7x(GEMM+bias+relu) -> tanh/100. 160 rows/block,
// 4 waves x (64n x 160r), 2 blocks/CU (R12 structure, fatter row tile).
// ---------------------------------------------------------------------------
__global__ __launch_bounds__(THREADS, 2)
void nerf_main(const float* __restrict__ x,
               const float* __restrict__ b_in,
               const float* __restrict__ b_hid,
               const float* __restrict__ b_out,
               const unsigned char* __restrict__ ws,
               float* __restrict__ out, int nrows) {
    __shared__ __align__(16) unsigned char actL[81920];

    const int tid  = threadIdx.x;
    const int lane = tid & 63;
    const int wv   = tid >> 6;            // 0..3 (= ng)
    const int l31  = lane & 31;
    const int hi   = lane >> 5;
    const int hi16 = hi << 4;
    const int rswz  = (l31 & 15) << 3;    // 8B-granular act swizzle (phase 0)
    const int rswz2 = rswz ^ 8;
    const int nblk = wv * 64;
    const int gr0  = blockIdx.x * BR;

    const int vB = lane * 16;             // frag B-read base
    const int vW = l31 * 16 + hi * 8;     // frag epilogue write base

    // ---- positional encoding: row-major body (3 passes, rows 0..159) ----
    #pragma unroll
    for (int pass = 0; pass < 3; ++pass) {
        const int rr = (tid >> 2) + pass * 64;   // 0..191
        if (rr < BR) {
            const int part = tid & 3;
            const int co = part >> 1, hf = part & 1;
            const int grow = gr0 + rr;
            float xv = (grow < nrows) ? x[(size_t)grow * 2 + co] : 0.f;
            const int rowo = rr * 512;
            const int rsw = (rr & 15) << 3;
            const int kb = co * 20 + hf * 10;
            float vv[10];
            #pragma unroll
            for (int f = 0; f < 10; ++f) {
                float ang = xv * (float)(1 << f);
                vv[f] = hf ? __cosf(ang) : __sinf(ang);
            }
            #pragma unroll
            for (int p = 0; p < 5; ++p) {
                unsigned int u = cvt_pk_bf16(vv[2 * p], vv[2 * p + 1]);
                int byte = (kb + 2 * p) * 2;
                *(unsigned int*)&actL[rowo + (byte ^ rsw)] = u;
            }
            int z = 80 + part * 12;           // zero-pad bytes [80,128)
            *(unsigned int*)&actL[rowo + ((z    ) ^ rsw)] = 0u;
            *(unsigned int*)&actL[rowo + ((z + 4) ^ rsw)] = 0u;
            *(unsigned int*)&actL[rowo + ((z + 8) ^ rsw)] = 0u;
        }
    }
    __syncthreads();

    f32x16 acc[2][5];
    const unsigned char* wstream = ws + wv * NG_STRIDE + lane * 16;

    // ---- layer 0: R7-proven row-major B-reads; frag epilogue ----
    {
        bias_init(b_in, acc, nblk, hi);
        int olo[4], ohi[4];
        #pragma unroll
        for (int kk = 0; kk < 4; ++kk) {
            const int bo = kk * 32 + hi16;
            olo[kk] = l31 * 512 + (bo ^ rswz);
            ohi[kk] = l31 * 512 + (bo ^ rswz2);
        }
        __builtin_amdgcn_s_setprio(1);
        #pragma unroll
        for (int kk = 0; kk < 4; ++kk) {
            const unsigned char* fp = wstream + kk * 2048;
            bf16x8 a0 = *(const bf16x8*)(fp);
            bf16x8 a1 = *(const bf16x8*)(fp + 1024);
            #pragma unroll
            for (int tr = 0; tr < 5; ++tr) {
                bf16x8 b = ld_act2(&actL[olo[kk] + tr * 16384],
                                   &actL[ohi[kk] + tr * 16384]);
                acc[0][tr] = __builtin_amdgcn_mfma_f32_32x32x16_bf16(a0, b, acc[0][tr], 0, 0, 0);
                acc[1][tr] = __builtin_amdgcn_mfma_f32_32x32x16_bf16(a1, b, acc[1][tr], 0, 0, 0);
            }
        }
        __builtin_amdgcn_s_setprio(0);
        __syncthreads();                  // all waves done reading row-major act
        epilogue_frag(acc, actL, vW, wv); // overwrite buffer with fragments
        __syncthreads();
        wstream += 8192;
    }

    // ---- layers 1..6 ----
    #pragma unroll 1
    for (int l = 0; l < 6; ++l) {
        hidden_layer(wstream, b_hid + l * 256,
                     actL, acc, vB, vW, wv, nblk, hi);
        wstream += 32768;
    }

    // ---- layer 7: frag B-reads -> tanh/100 -> out (wave 0 covers rb=4) ----
    for (int rb = wv; rb < 5; rb += 4) {
        f32x16 c0, c1;
        #pragma unroll
        for (int j = 0; j < 16; ++j) { c0[j] = 0.f; c1[j] = 0.f; }
        const unsigned char* wo = ws + WS_WOUT + lane * 16;
        #pragma unroll
        for (int kk = 0; kk < 16; ++kk) {
            bf16x8 a = *(const bf16x8*)(wo + kk * 1024);
            bf16x8 b = *(const bf16x8*)&actL[vB + (kk * 5 + rb) * 1024];
            if (kk & 1) c1 = __builtin_amdgcn_mfma_f32_32x32x16_bf16(a, b, c1, 0, 0, 0);
            else        c0 = __builtin_amdgcn_mfma_f32_32x32x16_bf16(a, b, c0, 0, 0, 0);
        }
        if (hi == 0) {
            const int row = gr0 + rb * 32 + l31;
            if (row < nrows) {
                float* op = out + (size_t)row * 3;
                #pragma unroll
                for (int j = 0; j < 3; ++j)
                    op[j] = tanhf(c0[j] + c1[j] + b_out[j]) * 0.01f;
            }
        }
    }
}

extern "C" void kernel_launch(void* const* d_in, const int* in_sizes, int n_in,
                              void* d_out, int out_size, void* d_ws, size_t ws_size,
                              hipStream_t stream) {
    (void)n_in; (void)out_size;
    const float* x     = (const float*)d_in[0];
    const float* W_in  = (const float*)d_in[1];
    const float* b_in  = (const float*)d_in[2];
    const float* W_hid = (const float*)d_in[3];
    const float* b_hid = (const float*)d_in[4];
    const float* W_out = (const float*)d_in[5];
    const float* b_out = (const float*)d_in[6];
    unsigned char* ws  = (unsigned char*)d_ws;
    float* out = (float*)d_out;

    if (ws_size < (size_t)WS_TOTAL) return;

    const int nrows = in_sizes[0] / 2;                // total points
    const int grid  = (nrows + BR - 1) / BR;

    prep_kernel<<<1632, 256, 0, stream>>>(W_in, W_hid, W_out, ws);
    nerf_main<<<grid, THREADS, 0, stream>>>(x, b_in, b_hid, b_out, ws, out, nrows);
}